// Round 13
// baseline (445.793 us; speedup 1.0000x reference)
//
#include <hip/hip_runtime.h>
#include <hip/hip_bf16.h>

#define BB 8192
#define SS 20
#define DD 300
#define JJ 512
#define NII 1000
#define VGG 2078
#define BP1 72           // k1 64x64 chunk lds row stride

typedef __attribute__((ext_vector_type(8))) short short8v;
typedef __attribute__((ext_vector_type(4))) float float4v;

__device__ __forceinline__ unsigned short bf16u(float x) {
    __hip_bfloat16 h = __float2bfloat16(x);
    return *(unsigned short*)&h;
}

// ---------------- combined pad+convert for W_emb (512 rows) + guide (1000 rows) -
__global__ __launch_bounds__(256) void kc_pad2(const float* __restrict__ W_emb,
                                               const float* __restrict__ guide,
                                               __hip_bfloat16* __restrict__ Web,
                                               __hip_bfloat16* __restrict__ Gb) {
    long idx = (long)blockIdx.x * 256 + threadIdx.x;
    if (idx >= 1512L * 2112) return;
    int r = (int)(idx / 2112), c = (int)(idx % 2112);
    if (r < JJ) {
        float v = (c < VGG) ? W_emb[(long)r * VGG + c] : 0.f;
        Web[(long)r * 2112 + c] = __float2bfloat16(v);
    } else {
        int g = r - JJ;
        float v = (c < VGG) ? guide[(long)g * VGG + c] : 0.f;
        Gb[(long)g * 2112 + c] = __float2bfloat16(v);
    }
}

// ---------------- Wt prep: B-fragment-transposed weights ----------------------
__global__ __launch_bounds__(256) void kc_prep_wt(const float* __restrict__ W_sent,
                                                  const float* __restrict__ b_sent,
                                                  const float* __restrict__ b_emb,
                                                  __hip_bfloat16* __restrict__ dst) {
    int idx = blockIdx.x * 256 + threadIdx.x;   // chunk id
    if (idx >= 40 * 512) return;
    int kb = idx >> 9, col = idx & 511;
#pragma unroll
    for (int e = 0; e < 8; ++e) {
        int k = kb * 8 + e;
        float v = (k < DD) ? W_sent[(long)col * DD + k]
                : (k == DD) ? b_sent[col]
                : (k == DD + 1) ? b_emb[col] : 0.f;
        dst[(long)idx * 8 + e] = __float2bfloat16(v);
    }
}

// ---------------- sum of w_fc (one block) --------------------------------------
__global__ __launch_bounds__(512) void kS_sumwf(const float* __restrict__ w_fc,
                                                float* __restrict__ out) {
    __shared__ float part[8];
    int t = threadIdx.x;
    float v = w_fc[t];
    v += __shfl_xor(v, 1);  v += __shfl_xor(v, 2);  v += __shfl_xor(v, 4);
    v += __shfl_xor(v, 8);  v += __shfl_xor(v, 16); v += __shfl_xor(v, 32);
    if ((t & 63) == 0) part[t >> 6] = v;
    __syncthreads();
    if (t == 0) {
        float s = 0.f;
#pragma unroll
        for (int i = 0; i < 8; ++i) s += part[i];
        out[0] = s;
    }
}

// ---------------- kernel 0: valid / nonzero masks ----------------
__global__ __launch_bounds__(256) void k0_valid(const int* __restrict__ labels,
                                                float* __restrict__ valid,
                                                float* __restrict__ nonzero) {
    int b = blockIdx.x * blockDim.x + threadIdx.x;
    if (b >= BB) return;
    float v = 1.f;
    for (int s = 0; s < SS; ++s) {
        float nz = (labels[b * SS + s] != 0) ? 1.f : 0.f;
        v *= nz;
        nonzero[b * SS + s] = nz;
        valid[b * SS + s] = v;
    }
}

// ---------------- kernel 1 (MFMA): femb = bf16(guide @ W_emb^T + b_emb) --------
__global__ __launch_bounds__(256) void k1_femb_mfma(
    const __hip_bfloat16* __restrict__ Gb,   // [NII][2112]
    const __hip_bfloat16* __restrict__ Web,  // [JJ][2112]
    const float* __restrict__ b_emb,
    __hip_bfloat16* __restrict__ femb) {     // [1024][JJ]
    __shared__ __hip_bfloat16 Al[64 * BP1];
    __shared__ __hip_bfloat16 Bl[64 * BP1];
    const int t = threadIdx.x;
    const int m0 = blockIdx.x * 64;
    const int n0 = blockIdx.y * 64;
    const int lane = t & 63;
    const int w = t >> 6;
    const int wm = w >> 1, wn = w & 1;
    const int li = lane & 15, lq = lane >> 4;

    float4v acc[2][2] = {};

    for (int kt = 0; kt < 33; ++kt) {
        for (int c = t; c < 512; c += 256) {
            int rr = c >> 3, off = (c & 7) * 8;
            int gr = m0 + rr; if (gr > NII - 1) gr = NII - 1;
            *(uint4*)&Al[rr * BP1 + off] =
                *(const uint4*)(Gb + (long)gr * 2112 + kt * 64 + off);
            *(uint4*)&Bl[rr * BP1 + off] =
                *(const uint4*)(Web + (long)(n0 + rr) * 2112 + kt * 64 + off);
        }
        __syncthreads();
#pragma unroll
        for (int ks = 0; ks < 2; ++ks) {
            short8v a[2], b[2];
#pragma unroll
            for (int mt = 0; mt < 2; ++mt)
                a[mt] = *(const short8v*)&Al[(wm * 32 + mt * 16 + li) * BP1 + ks * 32 + lq * 8];
#pragma unroll
            for (int nt = 0; nt < 2; ++nt)
                b[nt] = *(const short8v*)&Bl[(wn * 32 + nt * 16 + li) * BP1 + ks * 32 + lq * 8];
#pragma unroll
            for (int mt = 0; mt < 2; ++mt)
#pragma unroll
                for (int nt = 0; nt < 2; ++nt)
                    acc[mt][nt] = __builtin_amdgcn_mfma_f32_16x16x32_bf16(
                        a[mt], b[nt], acc[mt][nt], 0, 0, 0);
        }
        __syncthreads();
    }
#pragma unroll
    for (int nt = 0; nt < 2; ++nt) {
        int col = n0 + wn * 32 + nt * 16 + li;
        float be = b_emb[col];
#pragma unroll
        for (int mt = 0; mt < 2; ++mt)
#pragma unroll
            for (int reg = 0; reg < 4; ++reg) {
                int row = wm * 32 + mt * 16 + lq * 4 + reg;
                femb[(long)(m0 + row) * JJ + col] = __float2bfloat16(acc[mt][nt][reg] + be);
            }
    }
}

// ---------------- kernel 2 (MFMA): fused scores — zero LDS, clean pipeline ----
// 256 threads = 4 waves; block owns 64 m-rows (wave: 16). Wave sweeps all 512
// j-cols in 16 np-steps. ALL epilogue operands (femb pairs, w_fc) are hoisted
// into registers BEFORE the main loop, and the nq loop is fully unrolled, so
// the loop body's ONLY memory ops are the 20 B-frag loads per tile -> the
// compiler can use counted vmcnt waits and the 2-deep pipeline survives.
// (Round-12's per-np femb/w_fc loads forced a FIFO vmcnt drain every tile.)
__global__ __launch_bounds__(256)
__attribute__((amdgpu_waves_per_eu(2, 4)))
void k2_scores_mfma(
    const float* __restrict__ context,
    const __hip_bfloat16* __restrict__ Wt,   // frag-transposed [40*512] chunks
    const float* __restrict__ w_fc,
    const float* __restrict__ b_fc,
    const float* __restrict__ sumwf,
    const __hip_bfloat16* __restrict__ femb, // [1024][JJ]
    const int* __restrict__ ann,
    const float* __restrict__ valid,
    float* __restrict__ scores) {
    const int t = threadIdx.x;
    const int wid = t >> 6, lane = t & 63;
    const int li = lane & 15, lq = lane >> 4;
    const int m0 = blockIdx.x * 64 + wid * 16;

    // ---- C-row metadata ----
    const int mslot = m0 + lq * 4;
    const int b0r = mslot / SS;
    const int b3r = (mslot + 3) / SS;
    const int g0 = ann[2 * b0r];
    const int g1 = ann[2 * b3r];
    float vmc[4]; unsigned selm[4];
#pragma unroll
    for (int reg = 0; reg < 4; ++reg) {
        vmc[reg] = valid[mslot + reg];
        selm[reg] = (((mslot + reg) / SS) != b0r) ? 0xffffffffu : 0u;
    }

    // ---- preload ALL per-np epilogue operands into registers ----
    const unsigned short* fp = (const unsigned short*)femb;
    unsigned fA[16], fB[16], wpk[16];
#pragma unroll
    for (int np = 0; np < 16; ++np) {
        const int colA = np * 32 + li;
        const int colB = colA + 16;
        fA[np] = ((unsigned)fp[(long)g1 * JJ + colA] << 16) | fp[(long)g0 * JJ + colA];
        fB[np] = ((unsigned)fp[(long)g1 * JJ + colB] << 16) | fp[(long)g0 * JJ + colB];
        wpk[np] = ((unsigned)bf16u(w_fc[colB]) << 16) | bf16u(w_fc[colA]);
    }

    // ---- A fragments (row = li), f32 -> bf16 in regs; bias cols at k300/301 --
    const float* crow = context + (long)(m0 + li) * DD;
    const float vA = valid[m0 + li];
    short8v areg[10];
#pragma unroll
    for (int kt = 0; kt < 9; ++kt) {
        const int k0 = kt * 32 + lq * 8;
        float4 u = *(const float4*)(crow + k0);
        float4 v2 = *(const float4*)(crow + k0 + 4);
        short8v a;
        a[0] = (short)bf16u(u.x);  a[1] = (short)bf16u(u.y);
        a[2] = (short)bf16u(u.z);  a[3] = (short)bf16u(u.w);
        a[4] = (short)bf16u(v2.x); a[5] = (short)bf16u(v2.y);
        a[6] = (short)bf16u(v2.z); a[7] = (short)bf16u(v2.w);
        areg[kt] = a;
    }
    {   // kt=9: k 288..319, col300=1.0, col301=1-valid, rest 0
        short8v a = {0, 0, 0, 0, 0, 0, 0, 0};
        if (lq == 0) {
            float4 u = *(const float4*)(crow + 288);
            float4 v2 = *(const float4*)(crow + 292);
            a[0] = (short)bf16u(u.x);  a[1] = (short)bf16u(u.y);
            a[2] = (short)bf16u(u.z);  a[3] = (short)bf16u(u.w);
            a[4] = (short)bf16u(v2.x); a[5] = (short)bf16u(v2.y);
            a[6] = (short)bf16u(v2.z); a[7] = (short)bf16u(v2.w);
        } else if (lq == 1) {
            float4 u = *(const float4*)(crow + 296);
            a[0] = (short)bf16u(u.x);  a[1] = (short)bf16u(u.y);
            a[2] = (short)bf16u(u.z);  a[3] = (short)bf16u(u.w);
            a[4] = (short)bf16u(1.f);  a[5] = (short)bf16u(1.f - vA);
        }
        areg[9] = a;
    }

    const __hip_bfloat16* pb = Wt + ((long)lq * 512 + li) * 8;
    float sp[4] = {0.f, 0.f, 0.f, 0.f};

    auto loadB = [&](short8v (&buf)[20], int np) {
        const __hip_bfloat16* pn = pb + (long)np * 256;
#pragma unroll
        for (int kt = 0; kt < 10; ++kt) {
            buf[2 * kt]     = *(const short8v*)(pn + (long)kt * 16384);
            buf[2 * kt + 1] = *(const short8v*)(pn + (long)kt * 16384 + 128);
        }
    };
    // pure-register tile compute: 20 MFMA + epilogue (NO memory ops)
    auto computeB = [&](short8v (&buf)[20], unsigned uA, unsigned uB, unsigned wp) {
        float4v a0 = {0.f, 0.f, 0.f, 0.f}, a1 = {0.f, 0.f, 0.f, 0.f};
#pragma unroll
        for (int kt = 0; kt < 10; ++kt) {
            a0 = __builtin_amdgcn_mfma_f32_16x16x32_bf16(areg[kt], buf[2 * kt], a0, 0, 0, 0);
            a1 = __builtin_amdgcn_mfma_f32_16x16x32_bf16(areg[kt], buf[2 * kt + 1], a1, 0, 0, 0);
        }
        const float wfA = __uint_as_float(wp << 16);
        const float wfB = __uint_as_float(wp & 0xffff0000u);
        const unsigned floA = uA << 16, fhiA = uA & 0xffff0000u;
        const unsigned floB = uB << 16, fhiB = uB & 0xffff0000u;
#pragma unroll
        for (int reg = 0; reg < 4; ++reg) {
            const float fvA = __uint_as_float((floA & ~selm[reg]) | (fhiA & selm[reg]));
            const float xA = fmaf(vmc[reg], fvA, a0[reg]);
            const float eA = __expf(xA + xA);
            sp[reg] = fmaf(wfA, __builtin_amdgcn_rcpf(eA + 1.f), sp[reg]);
            const float fvB = __uint_as_float((floB & ~selm[reg]) | (fhiB & selm[reg]));
            const float xB = fmaf(vmc[reg], fvB, a1[reg]);
            const float eB = __expf(xB + xB);
            sp[reg] = fmaf(wfB, __builtin_amdgcn_rcpf(eB + 1.f), sp[reg]);
        }
    };

    short8v bufA[20], bufB[20];
    loadB(bufA, 0);
#pragma unroll
    for (int nq = 0; nq < 8; ++nq) {
        const int npA = nq * 2;
        loadB(bufB, npA + 1);                       // in flight under compute(bufA)
        computeB(bufA, fA[npA], fB[npA], wpk[npA]);
        if (npA + 2 < 16) loadB(bufA, npA + 2);     // in flight under compute(bufB)
        computeB(bufB, fA[npA + 1], fB[npA + 1], wpk[npA + 1]);
    }

    // ---- reduce over 16 li lanes, direct store ----
    const float base = b_fc[0] + sumwf[0];
#pragma unroll
    for (int reg = 0; reg < 4; ++reg) {
        float v = sp[reg];
        v += __shfl_xor(v, 1); v += __shfl_xor(v, 2);
        v += __shfl_xor(v, 4); v += __shfl_xor(v, 8);
        if (li == 0) scores[mslot + reg] = base - 2.f * v;
    }
}

// ---------------- kernel 3: softmax + mask + renorm + weighted sum -------------
__global__ __launch_bounds__(256) void k3_out(const float* __restrict__ scores,
                                              const float* __restrict__ nonzero,
                                              const float* __restrict__ embedded,
                                              float* __restrict__ out) {
    __shared__ float wgt[3][SS];
    const int b0 = blockIdx.x * 3;
    const int t = threadIdx.x;
    if (t < 3) {
        int b = b0 + t;
        if (b < BB) {
            float sc[SS], nz[SS];
            float mx = -1e30f;
            for (int s = 0; s < SS; ++s) {
                sc[s] = scores[b * SS + s];
                nz[s] = nonzero[b * SS + s];
                mx = fmaxf(mx, sc[s]);
            }
            float den = 0.f, e[SS];
            for (int s = 0; s < SS; ++s) { e[s] = nz[s] * __expf(sc[s] - mx); den += e[s]; }
            float inv = 1.f / den;
            for (int s = 0; s < SS; ++s) wgt[t][s] = e[s] * inv;
        }
    }
    __syncthreads();
    if (t < 225) {
        int r = t / 75, q = t - r * 75;
        int b = b0 + r;
        if (b < BB) {
            float4 a; a.x = a.y = a.z = a.w = 0.f;
#pragma unroll
            for (int s = 0; s < SS; ++s) {
                float4 e = *(const float4*)(embedded + ((long)b * SS + s) * DD + q * 4);
                float ww = wgt[r][s];
                a.x += ww * e.x; a.y += ww * e.y; a.z += ww * e.z; a.w += ww * e.w;
            }
            *(float4*)(out + (long)b * DD + q * 4) = a;
        }
    }
}

extern "C" void kernel_launch(void* const* d_in, const int* in_sizes, int n_in,
                              void* d_out, int out_size, void* d_ws, size_t ws_size,
                              hipStream_t stream) {
    const float* context  = (const float*)d_in[0];
    const float* embedded = (const float*)d_in[1];
    const int*   labels   = (const int*)d_in[2];
    const float* guide    = (const float*)d_in[3];
    const int*   ann      = (const int*)d_in[4];
    const float* W_sent   = (const float*)d_in[5];
    const float* b_sent   = (const float*)d_in[6];
    const float* W_emb    = (const float*)d_in[7];
    const float* b_emb    = (const float*)d_in[8];
    const float* w_fc     = (const float*)d_in[9];
    const float* b_fc     = (const float*)d_in[10];
    float* out = (float*)d_out;

    char* w = (char*)d_ws;
    __hip_bfloat16* femb = (__hip_bfloat16*)(w);               // 1024*512*2 = 1048576
    float* valid         = (float*)(w + 1048576);              // 655360
    float* nonzero       = (float*)(w + 1703936);              // 655360
    float* scores        = (float*)(w + 2359296);              // 655360
    __hip_bfloat16* Wt   = (__hip_bfloat16*)(w + 3014656);     // 40*512*8*2 = 327680
    __hip_bfloat16* Web  = (__hip_bfloat16*)(w + 3342336);     // 512*2112*2 = 2162688
    __hip_bfloat16* Gb   = (__hip_bfloat16*)(w + 5505024);     // 1000*2112*2= 4224000
    float* sums          = (float*)(w + 9729024);              // 4
    // total 9729028 bytes

    hipLaunchKernelGGL(kc_prep_wt, dim3((40 * 512 + 255) / 256), dim3(256), 0, stream,
                       W_sent, b_sent, b_emb, Wt);
    hipLaunchKernelGGL(kc_pad2, dim3((int)((1512L * 2112 + 255) / 256)), dim3(256), 0, stream,
                       W_emb, guide, Web, Gb);
    hipLaunchKernelGGL(kS_sumwf, dim3(1), dim3(512), 0, stream, w_fc, sums);
    hipLaunchKernelGGL(k0_valid, dim3(BB / 256), dim3(256), 0, stream,
                       labels, valid, nonzero);
    hipLaunchKernelGGL(k1_femb_mfma, dim3(16, JJ / 64), dim3(256), 0, stream,
                       Gb, Web, b_emb, femb);
    hipLaunchKernelGGL(k2_scores_mfma, dim3((BB * SS) / 64), dim3(256), 0, stream,
                       context, Wt, w_fc, b_fc, sums, femb, ann, valid, scores);
    hipLaunchKernelGGL(k3_out, dim3((BB + 2) / 3), dim3(256), 0, stream,
                       scores, nonzero, embedded, out);
}